// Round 1
// baseline (147.824 us; speedup 1.0000x reference)
//
#include <hip/hip_runtime.h>

// FoveatedSamplingConv2d on MI355X (gfx950)
// out[b,o,h,w] = bias[o] + sum_{c,k,l} x[b,c,clip(h+offy(k,l)),clip(w+offx(k,l))] * W[o,c,k,l]
// Coords recomputed in-kernel (deterministic), sy/sx inputs ignored.

#define HH 256
#define WW 256
#define IN_C 3
#define OUT_C 64
#define KS 11
#define BB 4

// Transpose weight (O,C,K,K) -> (C*K*K, O) so each tap's 64 output-channel
// weights are contiguous and loaded via uniform (scalar) loads.
__global__ void fovconv_transpose_w(const float* __restrict__ w,
                                    float* __restrict__ wT) {
    int i = blockIdx.x * 256 + threadIdx.x;
    const int N = OUT_C * IN_C * KS * KS;
    if (i < N) {
        int o  = i / (IN_C * KS * KS);
        int ct = i % (IN_C * KS * KS);
        wT[ct * OUT_C + o] = w[i];
    }
}

__global__ void __launch_bounds__(256)
fovconv_main(const float* __restrict__ x, const float* __restrict__ wT,
             const float* __restrict__ bias, float* __restrict__ out) {
    const int wpix = threadIdx.x;          // w coordinate, 0..255
    const int h    = blockIdx.x & (HH - 1);
    const int b    = blockIdx.x >> 8;

    float acc[OUT_C];
#pragma unroll
    for (int o = 0; o < OUT_C; ++o) acc[o] = 0.f;

    const float* xb = x + (size_t)b * IN_C * HH * WW;

    for (int k = 0; k < KS; ++k) {
        const int dy = k - 5;
        for (int l = 0; l < KS; ++l) {
            const int dx = l - 5;
            const int d  = max(abs(dy), abs(dx));
            const int scale = (d <= 1) ? 1 : (d == 2 ? 3 : (d == 3 ? 5 : 7));
            const int sy = min(max(h + dy * scale, 0), HH - 1);
            const int sx = min(max(wpix + dx * scale, 0), WW - 1);
            const int base = sy * WW + sx;
            const int t = k * KS + l;
#pragma unroll
            for (int c = 0; c < IN_C; ++c) {
                const float xv = xb[c * (HH * WW) + base];
                // uniform address -> scalar loads (s_load_dwordx16 chunks)
                const float* wp = wT + (c * (KS * KS) + t) * OUT_C;
#pragma unroll
                for (int o = 0; o < OUT_C; ++o)
                    acc[o] = fmaf(xv, wp[o], acc[o]);
            }
        }
    }

    // out[b][o][h][w]; stores coalesced across threadIdx.x per o
    float* op = out + (((size_t)b * OUT_C) * HH + h) * WW + wpix;
#pragma unroll
    for (int o = 0; o < OUT_C; ++o)
        op[(size_t)o * HH * WW] = acc[o] + bias[o];
}

extern "C" void kernel_launch(void* const* d_in, const int* in_sizes, int n_in,
                              void* d_out, int out_size, void* d_ws, size_t ws_size,
                              hipStream_t stream) {
    const float* x    = (const float*)d_in[0];
    const float* wgt  = (const float*)d_in[1];
    const float* bias = (const float*)d_in[2];
    // d_in[3] = sy, d_in[4] = sx : ignored (recomputed in-kernel)
    float* out = (float*)d_out;
    float* wT  = (float*)d_ws;   // needs 64*363*4 = 92928 bytes

    const int NW = OUT_C * IN_C * KS * KS;
    fovconv_transpose_w<<<(NW + 255) / 256, 256, 0, stream>>>(wgt, wT);
    fovconv_main<<<BB * HH, 256, 0, stream>>>(x, wT, bias, out);
}

// Round 2
// 56.579 us; speedup vs baseline: 2.6127x; 2.6127x over previous
//
#include <hip/hip_runtime.h>

// FoveatedSamplingConv2d — bf16 MFMA implicit GEMM (gfx950)
// out[b,o,h,w] = bias[o] + sum_{c,ky,kx} x[b,c,clip(h+dy),clip(w+dx)] * W[o,c,ky,kx]
// M = out channels (A = weights, pre-fragmented), N = pixels (B = gathered x),
// K = 3*128 (121 taps + 7 zero-pad per channel).

#define HH 256
#define WW 256
#define INC 3
#define OC 64
#define KS 11
#define BB 4
#define KPC 128          // padded taps per input channel
#define NKC 12           // K chunks of 32 (3*128/32)

typedef __attribute__((ext_vector_type(4))) float f32x4;
typedef __attribute__((ext_vector_type(8))) short s16x8;
typedef unsigned int u32;
typedef unsigned short u16;

static __device__ __forceinline__ u16 f2bf(float f) {
    u32 u = __builtin_bit_cast(u32, f);
    u32 r = (u + 0x7FFFu + ((u >> 16) & 1u)) >> 16;   // RTNE (finite data)
    return (u16)r;
}

// ---- prep: x fp32 -> bf16 (same layout) --------------------------------
__global__ void cvt_x(const float* __restrict__ x, u16* __restrict__ xb) {
    int i = blockIdx.x * 256 + threadIdx.x;          // float4 index
    float4 v = ((const float4*)x)[i];
    ushort4 o;
    o.x = f2bf(v.x); o.y = f2bf(v.y); o.z = f2bf(v.z); o.w = f2bf(v.w);
    ((ushort4*)xb)[i] = o;
}

// ---- prep: W (O,C,11,11) fp32 -> bf16 A-fragment order ------------------
// wf flat idx = ((kc*4 + ot)*64 + lane)*8 + j
// o = ot*16 + (lane&15) ; k = kc*32 + (lane>>4)*8 + j ; c = k>>7 ; tt = k&127
__global__ void prep_wfrag(const float* __restrict__ w, u16* __restrict__ wf) {
    int i = blockIdx.x * 256 + threadIdx.x;          // 0..24575
    int j    = i & 7;
    int lane = (i >> 3) & 63;
    int ot   = (i >> 9) & 3;
    int kc   = i >> 11;
    int o  = ot * 16 + (lane & 15);
    int k  = kc * 32 + ((lane >> 4) << 3) + j;
    int c  = k >> 7;
    int tt = k & 127;
    float val = 0.f;
    if (tt < 121) {
        int ky = tt / 11, kx = tt % 11;
        val = w[((o * INC + c) * KS + ky) * KS + kx];
    }
    wf[i] = f2bf(val);
}

// ---- main: 256 thr = 4 waves; wave = 16 pixels (one h row segment) ------
__global__ void __launch_bounds__(256)
fov_mfma(const u16* __restrict__ xb, const u16* __restrict__ wf,
         const float* __restrict__ bias, float* __restrict__ out) {
    __shared__ u16 offPk[KPC];
    const int tid = threadIdx.x;
    if (tid < KPC) {                      // per-tap packed offsets (dy,dx)
        int tt = tid, dy = 0, dx = 0;
        if (tt < 121) {
            int ky = tt / 11, kx = tt % 11;
            int ay = ky - 5, ax = kx - 5;
            int d = max(abs(ay), abs(ax));
            int sc = (d <= 1) ? 1 : (d == 2 ? 3 : (d == 3 ? 5 : 7));
            dy = ay * sc; dx = ax * sc;
        }
        offPk[tt] = (u16)(((dy + 64) << 8) | (dx + 64));
    }
    __syncthreads();

    const int lane = tid & 63;
    const int wv   = tid >> 6;
    const int h    = (blockIdx.x >> 2) & (HH - 1);
    const int b    = blockIdx.x >> 10;
    const int w0   = (blockIdx.x & 3) * 64 + wv * 16;
    const int wpix = w0 + (lane & 15);
    const int tgrp = (lane >> 4) << 3;    // k-subgroup base 0/8/16/24

    const u16* xbb = xb + b * (INC * HH * WW);

    f32x4 acc0 = {0,0,0,0}, acc1 = {0,0,0,0}, acc2 = {0,0,0,0}, acc3 = {0,0,0,0};

    for (int kc = 0; kc < NKC; ++kc) {
        const int c  = kc >> 2;
        const int t0 = ((kc & 3) << 5) + tgrp;

        // A-fragments (weights, identical for every wave/block -> L1/L2)
        const s16x8* wfp = ((const s16x8*)wf) + ((kc << 8) + lane);
        s16x8 a0 = wfp[0], a1 = wfp[64], a2 = wfp[128], a3 = wfp[192];

        // B-fragment: gather 8 taps for this lane's pixel
        s16x8 pv = *(const s16x8*)&offPk[t0];
        u32 g[8];
#pragma unroll
        for (int j = 0; j < 8; ++j) {
            int pkj = (int)(u16)pv[j];
            int dy = (pkj >> 8) - 64;
            int dx = (pkj & 255) - 64;
            int sy = min(max(h + dy, 0), HH - 1);
            int sx = min(max(wpix + dx, 0), WW - 1);
            g[j] = xbb[(c << 16) + (sy << 8) + sx];
        }
        union { u32 u[4]; s16x8 v; } bu;
        bu.u[0] = g[0] | (g[1] << 16);
        bu.u[1] = g[2] | (g[3] << 16);
        bu.u[2] = g[4] | (g[5] << 16);
        bu.u[3] = g[6] | (g[7] << 16);

        acc0 = __builtin_amdgcn_mfma_f32_16x16x32_bf16(a0, bu.v, acc0, 0, 0, 0);
        acc1 = __builtin_amdgcn_mfma_f32_16x16x32_bf16(a1, bu.v, acc1, 0, 0, 0);
        acc2 = __builtin_amdgcn_mfma_f32_16x16x32_bf16(a2, bu.v, acc2, 0, 0, 0);
        acc3 = __builtin_amdgcn_mfma_f32_16x16x32_bf16(a3, bu.v, acc3, 0, 0, 0);
    }

    // D: col = lane&15 = pixel, row = (lane>>4)*4 + r = o within 16-tile
    const int orow = (lane >> 4) << 2;
    float* op = out + (size_t)b * OC * HH * WW + h * WW + wpix;
#pragma unroll
    for (int r = 0; r < 4; ++r) {
        int o0 = orow + r;
        op[(size_t)(o0)      * (HH * WW)] = acc0[r] + bias[o0];
        op[(size_t)(o0 + 16) * (HH * WW)] = acc1[r] + bias[o0 + 16];
        op[(size_t)(o0 + 32) * (HH * WW)] = acc2[r] + bias[o0 + 32];
        op[(size_t)(o0 + 48) * (HH * WW)] = acc3[r] + bias[o0 + 48];
    }
}

// ---------------- fallback (R1 fp32 path, if ws too small) ---------------
__global__ void fovconv_transpose_w(const float* __restrict__ w,
                                    float* __restrict__ wT) {
    int i = blockIdx.x * 256 + threadIdx.x;
    const int N = OC * INC * KS * KS;
    if (i < N) {
        int o  = i / (INC * KS * KS);
        int ct = i % (INC * KS * KS);
        wT[ct * OC + o] = w[i];
    }
}

__global__ void __launch_bounds__(256)
fovconv_main(const float* __restrict__ x, const float* __restrict__ wT,
             const float* __restrict__ bias, float* __restrict__ out) {
    const int wpix = threadIdx.x;
    const int h    = blockIdx.x & (HH - 1);
    const int b    = blockIdx.x >> 8;
    float acc[OC];
#pragma unroll
    for (int o = 0; o < OC; ++o) acc[o] = 0.f;
    const float* xbp = x + (size_t)b * INC * HH * WW;
    for (int k = 0; k < KS; ++k) {
        const int dy = k - 5;
        for (int l = 0; l < KS; ++l) {
            const int dx = l - 5;
            const int d  = max(abs(dy), abs(dx));
            const int scale = (d <= 1) ? 1 : (d == 2 ? 3 : (d == 3 ? 5 : 7));
            const int sy = min(max(h + dy * scale, 0), HH - 1);
            const int sx = min(max(wpix + dx * scale, 0), WW - 1);
            const int base = sy * WW + sx;
            const int t = k * KS + l;
#pragma unroll
            for (int c = 0; c < INC; ++c) {
                const float xv = xbp[c * (HH * WW) + base];
                const float* wp = wT + (c * (KS * KS) + t) * OC;
#pragma unroll
                for (int o = 0; o < OC; ++o)
                    acc[o] = fmaf(xv, wp[o], acc[o]);
            }
        }
    }
    float* op = out + (((size_t)b * OC) * HH + h) * WW + wpix;
#pragma unroll
    for (int o = 0; o < OC; ++o)
        op[(size_t)o * HH * WW] = acc[o] + bias[o];
}

extern "C" void kernel_launch(void* const* d_in, const int* in_sizes, int n_in,
                              void* d_out, int out_size, void* d_ws, size_t ws_size,
                              hipStream_t stream) {
    const float* x    = (const float*)d_in[0];
    const float* wgt  = (const float*)d_in[1];
    const float* bias = (const float*)d_in[2];
    float* out = (float*)d_out;

    const size_t xb_bytes = (size_t)BB * INC * HH * WW * 2;       // 1572864
    const size_t wf_bytes = (size_t)NKC * 4 * 64 * 8 * 2;         // 49152

    if (ws_size >= xb_bytes + wf_bytes) {
        u16* xbuf = (u16*)d_ws;
        u16* wf   = (u16*)((char*)d_ws + xb_bytes);
        cvt_x<<<(BB * INC * HH * WW / 4) / 256, 256, 0, stream>>>(x, xbuf);
        prep_wfrag<<<(NKC * 4 * 64 * 8) / 256, 256, 0, stream>>>(wgt, wf);
        fov_mfma<<<BB * HH * (WW / 64), 256, 0, stream>>>(xbuf, wf, bias, out);
    } else {
        float* wT = (float*)d_ws;
        const int NW = OC * INC * KS * KS;
        fovconv_transpose_w<<<(NW + 255) / 256, 256, 0, stream>>>(wgt, wT);
        fovconv_main<<<BB * HH, 256, 0, stream>>>(x, wT, bias, out);
    }
}